// Round 5
// baseline (111.828 us; speedup 1.0000x reference)
//
#include <hip/hip_runtime.h>

// Varlen non-causal attention, qkv-packed (T,3,H,D) fp32 in/out.
// 3-kernel pipeline:
//  1) prep:   fp32 qkv -> bf16 Qb[t][h][d] (x0.125 folded), Kb[h][t][d], Vtb[h][d][t]
//  2) main:   bf16 MFMA flash attention, TQ=128 (2 m-tiles/wave), split-K x4;
//             K/V staged via global_load_lds(16B), XOR-swizzled LDS (conflict-free
//             for both DMA writes and b128 fragment reads); K/V fragments are
//             read once per nt and feed both m-tiles (halves LDS reads / MFMA).
//  3) combine: merge split-K partials (m,l,O) -> out

#define HEADS 8
#define DH 64
#define TQ 128
#define TK 64
#define PSTR 72
#define NSPLIT 4
#define NEG_BIG -1e30f
#define L2E 1.44269504088896340736f

using f32x4 = __attribute__((ext_vector_type(4))) float;
using s16x8 = __attribute__((ext_vector_type(8))) short;

__device__ inline unsigned short bf16b(float x) {
    union { float f; unsigned u; } c; c.f = x;
    unsigned r = c.u + 0x7fffu + ((c.u >> 16) & 1u);   // RNE
    return (unsigned short)(r >> 16);
}

#if __has_builtin(__builtin_amdgcn_cvt_pk_bf16_f32)
__device__ inline unsigned pk2(float a, float b) {
    auto v = __builtin_amdgcn_cvt_pk_bf16_f32(a, b);
    unsigned u; __builtin_memcpy(&u, &v, 4); return u;
}
#else
__device__ inline unsigned pk2(float a, float b) {
    return (unsigned)bf16b(a) | ((unsigned)bf16b(b) << 16);
}
#endif

// ---------------- pre-pass: convert + re-layout ----------------
__global__ __launch_bounds__(256)
void prep_kernel(const float* __restrict__ qkv, unsigned short* __restrict__ Qb,
                 unsigned short* __restrict__ Kb, unsigned short* __restrict__ Vtb,
                 int T) {
    __shared__ unsigned short Lt[64][PSTR];
    const int m = blockIdx.z, h = blockIdx.y, t0 = blockIdx.x * 64;
    const int tid = threadIdx.x, d8 = tid & 7, tr = tid >> 3;   // tr 0..31

    #pragma unroll
    for (int i = 0; i < 2; ++i) {
        int t = t0 + i * 32 + tr;
        int tc = t < T ? t : T - 1;
        const float* src = qkv + ((size_t)tc * 3 + m) * (HEADS * DH) + h * DH + d8 * 8;
        float4 a = *(const float4*)src;
        float4 b = *(const float4*)(src + 4);
        if (m == 0) {
            a.x *= 0.125f; a.y *= 0.125f; a.z *= 0.125f; a.w *= 0.125f;
            b.x *= 0.125f; b.y *= 0.125f; b.z *= 0.125f; b.w *= 0.125f;
        }
        unsigned p0 = pk2(a.x, a.y), p1 = pk2(a.z, a.w);
        unsigned p2 = pk2(b.x, b.y), p3 = pk2(b.z, b.w);
        if (m == 2) {
            *(uint2*)&Lt[i * 32 + tr][d8 * 8]     = make_uint2(p0, p1);
            *(uint2*)&Lt[i * 32 + tr][d8 * 8 + 4] = make_uint2(p2, p3);
        } else if (t < T) {
            unsigned short* dst = (m == 0)
                ? (Qb + (size_t)t * (HEADS * DH) + h * DH + d8 * 8)
                : (Kb + ((size_t)h * T + t) * DH + d8 * 8);
            *(uint4*)dst = make_uint4(p0, p1, p2, p3);
        }
    }
    if (m == 2) {
        __syncthreads();
        const int d = tid >> 2, tg = tid & 3;
        #pragma unroll
        for (int p = 0; p < 2; ++p) {
            int G = tg + 4 * p;
            int td = t0 + G * 8;
            unsigned u[4];
            #pragma unroll
            for (int jj = 0; jj < 4; ++jj)
                u[jj] = (unsigned)Lt[G * 8 + 2 * jj][d] |
                        ((unsigned)Lt[G * 8 + 2 * jj + 1][d] << 16);
            if (td < T)
                *(uint4*)(Vtb + ((size_t)h * DH + d) * T + td) =
                    make_uint4(u[0], u[1], u[2], u[3]);
        }
    }
}

// ---------------- main flash kernel ----------------
__global__ __launch_bounds__(256, 4)
void fa_main(const unsigned short* __restrict__ Qb, const unsigned short* __restrict__ Kb,
             const unsigned short* __restrict__ Vtb, const int* __restrict__ cu,
             int n_cu, int T, float* __restrict__ out,
             float* __restrict__ Opart, float* __restrict__ Mp, float* __restrict__ Lp) {
    __shared__ unsigned short Ksh[TK * DH];   // swizzled granules: g = row*8 + (gd^(row&7))
    __shared__ unsigned short Vsh[DH * TK];
    __shared__ unsigned short Psh[TQ][PSTR];

    const int tid = threadIdx.x;
    const int h = blockIdx.y, t0 = blockIdx.x * TQ;
    const int split = blockIdx.z, nsplit = gridDim.z;
    const int w = tid >> 6, lane = tid & 63, n15 = lane & 15, quad = lane >> 4;

    // ---- per-lane segment bounds for the 2 m-tiles ----
    int lo[2], hi[2];
    #pragma unroll
    for (int mt = 0; mt < 2; ++mt) {
        int trow = t0 + w * 32 + mt * 16 + n15; if (trow > T - 1) trow = T - 1;
        int s = 0;
        for (int j = 1; j < n_cu - 1; ++j) if (cu[j] <= trow) s = j;
        lo[mt] = cu[s]; hi[mt] = cu[s + 1];
    }
    int kb_, ke;
    { int s = 0; for (int j = 1; j < n_cu - 1; ++j) if (cu[j] <= t0) s = j;
      kb_ = cu[s];
      int tl = t0 + TQ - 1; if (tl > T - 1) tl = T - 1;
      s = 0; for (int j = 1; j < n_cu - 1; ++j) if (cu[j] <= tl) s = j;
      ke = cu[s + 1]; }

    // ---- Q fragments (bf16, pre-scaled) ----
    s16x8 qfrag[2][2];
    #pragma unroll
    for (int mt = 0; mt < 2; ++mt) {
        int tc = t0 + w * 32 + mt * 16 + n15; if (tc > T - 1) tc = T - 1;
        const unsigned short* qp = Qb + (size_t)tc * (HEADS * DH) + h * DH + quad * 8;
        qfrag[mt][0] = *(const s16x8*)qp;
        qfrag[mt][1] = *(const s16x8*)(qp + 32);
    }

    // ---- staging lane constants ----
    const unsigned short* kb_h = Kb + (size_t)h * T * DH;
    const unsigned short* vt_h = Vtb + (size_t)h * DH * T;
    int krow_rel[2], vkey_off[2];
    const unsigned short* kbase[2];
    const unsigned short* vbase[2];
    #pragma unroll
    for (int i = 0; i < 2; ++i) {
        int gg = i * 64 + lane;
        int rr = gg >> 3;
        int gc = gg & 7;
        int row = w * 16 + rr;            // 0..63
        int gcol = gc ^ (row & 7);
        krow_rel[i] = row;
        kbase[i] = kb_h + gcol * 8;
        vbase[i] = vt_h + (size_t)row * T;
        vkey_off[i] = gcol * 8;
    }
    int off16[2];
    #pragma unroll
    for (int kh = 0; kh < 2; ++kh)
        off16[kh] = n15 * 128 + (((kh * 4 + quad) ^ (n15 & 7)) * 16);

    f32x4 oacc[2][4];
    #pragma unroll
    for (int mt = 0; mt < 2; ++mt)
        #pragma unroll
        for (int i = 0; i < 4; ++i) oacc[mt][i] = (f32x4){0.f, 0.f, 0.f, 0.f};
    float m_[2] = {NEG_BIG, NEG_BIG}, l_[2] = {0.f, 0.f};

    const int c0_start = (kb_ / TK) * TK + split * TK;
    for (int c0 = c0_start; c0 < ke; c0 += nsplit * TK) {
        // ---- async stage K + Vt ----
        #pragma unroll
        for (int i = 0; i < 2; ++i) {
            int rk = c0 + krow_rel[i]; if (rk > T - 1) rk = T - 1;
            __builtin_amdgcn_global_load_lds(
                (const __attribute__((address_space(1))) void*)(kbase[i] + ((size_t)rk << 6)),
                (__attribute__((address_space(3))) void*)&Ksh[(w * 128 + i * 64) * 8],
                16, 0, 0);
            int kv = c0 + vkey_off[i]; if (kv > T - 8) kv = T - 8;
            __builtin_amdgcn_global_load_lds(
                (const __attribute__((address_space(1))) void*)(vbase[i] + kv),
                (__attribute__((address_space(3))) void*)&Vsh[(w * 128 + i * 64) * 8],
                16, 0, 0);
        }
        __syncthreads();

        // ---- S^T = K·Q^T for both m-tiles; K frags read once per nt ----
        const char* Kc = (const char*)Ksh;
        f32x4 sacc[2][4];
        #pragma unroll
        for (int nt = 0; nt < 4; ++nt) {
            s16x8 k0 = *(const s16x8*)(Kc + nt * 2048 + off16[0]);
            s16x8 k1 = *(const s16x8*)(Kc + nt * 2048 + off16[1]);
            #pragma unroll
            for (int mt = 0; mt < 2; ++mt) {
                f32x4 z = (f32x4){0.f, 0.f, 0.f, 0.f};
                z = __builtin_amdgcn_mfma_f32_16x16x32_bf16(k0, qfrag[mt][0], z, 0, 0, 0);
                z = __builtin_amdgcn_mfma_f32_16x16x32_bf16(k1, qfrag[mt][1], z, 0, 0, 0);
                sacc[mt][nt] = z;
            }
        }

        // ---- mask + online softmax + P write, per m-tile ----
        #pragma unroll
        for (int mt = 0; mt < 2; ++mt) {
            if (!(c0 >= lo[mt] && c0 + TK <= hi[mt])) {
                #pragma unroll
                for (int nt = 0; nt < 4; ++nt)
                    #pragma unroll
                    for (int reg = 0; reg < 4; ++reg) {
                        int key = c0 + nt * 16 + quad * 4 + reg;
                        bool valid = (key >= lo[mt]) && (key < hi[mt]);
                        sacc[mt][nt][reg] = valid ? sacc[mt][nt][reg] : NEG_BIG;
                    }
            }
            float rm = NEG_BIG;
            #pragma unroll
            for (int nt = 0; nt < 4; ++nt)
                #pragma unroll
                for (int reg = 0; reg < 4; ++reg) rm = fmaxf(rm, sacc[mt][nt][reg]);
            rm = fmaxf(rm, __shfl_xor(rm, 16));
            rm = fmaxf(rm, __shfl_xor(rm, 32));
            float mn = fmaxf(m_[mt], rm);
            float alpha = exp2f((m_[mt] - mn) * L2E);
            float mnl = mn * L2E;
            float rs = 0.f;
            int prow = w * 32 + mt * 16 + n15;
            #pragma unroll
            for (int nt = 0; nt < 4; ++nt) {
                float p0 = exp2f(fmaf(sacc[mt][nt][0], L2E, -mnl));
                float p1 = exp2f(fmaf(sacc[mt][nt][1], L2E, -mnl));
                float p2 = exp2f(fmaf(sacc[mt][nt][2], L2E, -mnl));
                float p3 = exp2f(fmaf(sacc[mt][nt][3], L2E, -mnl));
                rs += (p0 + p1) + (p2 + p3);
                *(uint2*)&Psh[prow][nt * 16 + quad * 4] =
                    make_uint2(pk2(p0, p1), pk2(p2, p3));
            }
            rs += __shfl_xor(rs, 16);
            rs += __shfl_xor(rs, 32);
            l_[mt] = fmaf(l_[mt], alpha, rs);
            m_[mt] = mn;
            #pragma unroll
            for (int reg = 0; reg < 4; ++reg) {
                float ar = __shfl(alpha, quad * 4 + reg);
                oacc[mt][0][reg] *= ar; oacc[mt][1][reg] *= ar;
                oacc[mt][2][reg] *= ar; oacc[mt][3][reg] *= ar;
            }
        }

        // ---- PV: O += P·V ; V frags read once per nt ----
        s16x8 afr[2][2];
        #pragma unroll
        for (int mt = 0; mt < 2; ++mt) {
            afr[mt][0] = *(const s16x8*)&Psh[w * 32 + mt * 16 + n15][quad * 8];
            afr[mt][1] = *(const s16x8*)&Psh[w * 32 + mt * 16 + n15][32 + quad * 8];
        }
        const char* Vc = (const char*)Vsh;
        #pragma unroll
        for (int nt = 0; nt < 4; ++nt) {
            s16x8 v0 = *(const s16x8*)(Vc + nt * 2048 + off16[0]);
            s16x8 v1 = *(const s16x8*)(Vc + nt * 2048 + off16[1]);
            #pragma unroll
            for (int mt = 0; mt < 2; ++mt) {
                oacc[mt][nt] = __builtin_amdgcn_mfma_f32_16x16x32_bf16(afr[mt][0], v0, oacc[mt][nt], 0, 0, 0);
                oacc[mt][nt] = __builtin_amdgcn_mfma_f32_16x16x32_bf16(afr[mt][1], v1, oacc[mt][nt], 0, 0, 0);
            }
        }
        __syncthreads();
    }

    // ---- epilogue ----
    #pragma unroll
    for (int mt = 0; mt < 2; ++mt) {
        if (nsplit == 1) {
            #pragma unroll
            for (int reg = 0; reg < 4; ++reg) {
                float lr = __shfl(l_[mt], quad * 4 + reg);
                float inv = 1.f / fmaxf(lr, 1e-30f);
                int t = t0 + w * 32 + mt * 16 + quad * 4 + reg;
                if (t < T) {
                    #pragma unroll
                    for (int nt = 0; nt < 4; ++nt)
                        out[((size_t)t * HEADS + h) * DH + nt * 16 + n15] = oacc[mt][nt][reg] * inv;
                }
            }
        } else {
            #pragma unroll
            for (int reg = 0; reg < 4; ++reg) {
                int t = t0 + w * 32 + mt * 16 + quad * 4 + reg;
                if (t < T) {
                    size_t base = (((size_t)split * T + t) * HEADS + h) * DH;
                    #pragma unroll
                    for (int nt = 0; nt < 4; ++nt)
                        Opart[base + nt * 16 + n15] = oacc[mt][nt][reg];
                }
            }
            int tq = t0 + w * 32 + mt * 16 + n15;
            if (quad == 0 && tq < T) {
                size_t mi = ((size_t)split * T + tq) * HEADS + h;
                Mp[mi] = m_[mt]; Lp[mi] = l_[mt];
            }
        }
    }
}

// ---------------- split-K combine ----------------
__global__ __launch_bounds__(256)
void fa_combine_kernel(const float* __restrict__ Opart, const float* __restrict__ Mp,
                       const float* __restrict__ Lp, float* __restrict__ out, int T) {
    int i4 = blockIdx.x * blockDim.x + threadIdx.x;
    int total = T * HEADS * (DH / 4);
    if (i4 >= total) return;
    int th = i4 / (DH / 4);
    int d4 = i4 - th * (DH / 4);
    size_t stride = (size_t)T * HEADS * DH;
    int mlstride = T * HEADS;
    float m[NSPLIT], l[NSPLIT];
    float M = NEG_BIG;
    #pragma unroll
    for (int s = 0; s < NSPLIT; ++s) {
        m[s] = Mp[(size_t)s * mlstride + th];
        l[s] = Lp[(size_t)s * mlstride + th];
        M = fmaxf(M, m[s]);
    }
    float L = 0.f, wgt[NSPLIT];
    #pragma unroll
    for (int s = 0; s < NSPLIT; ++s) {
        wgt[s] = exp2f((m[s] - M) * L2E);
        L = fmaf(l[s], wgt[s], L);
    }
    float inv = 1.f / fmaxf(L, 1e-30f);
    size_t off = (size_t)th * DH + 4 * d4;
    float4 o = make_float4(0.f, 0.f, 0.f, 0.f);
    #pragma unroll
    for (int s = 0; s < NSPLIT; ++s) {
        float4 a = *(const float4*)&Opart[(size_t)s * stride + off];
        float ws = wgt[s];
        o.x = fmaf(a.x, ws, o.x); o.y = fmaf(a.y, ws, o.y);
        o.z = fmaf(a.z, ws, o.z); o.w = fmaf(a.w, ws, o.w);
    }
    o.x *= inv; o.y *= inv; o.z *= inv; o.w *= inv;
    *(float4*)&out[off] = o;
}

extern "C" void kernel_launch(void* const* d_in, const int* in_sizes, int n_in,
                              void* d_out, int out_size, void* d_ws, size_t ws_size,
                              hipStream_t stream) {
    const float* qkv = (const float*)d_in[0];
    const int* cu    = (const int*)d_in[1];
    const int n_cu   = in_sizes[1];
    const int T      = in_sizes[0] / (3 * HEADS * DH);
    float* out       = (float*)d_out;

    size_t elems = (size_t)T * HEADS * DH;

    float* Opart = (float*)d_ws;                                  // NSPLIT*elems f32
    float* Mpp   = Opart + (size_t)NSPLIT * elems;                // NSPLIT*T*H f32
    float* Lpp   = Mpp + (size_t)NSPLIT * T * HEADS;
    unsigned short* Qb  = (unsigned short*)(Lpp + (size_t)NSPLIT * T * HEADS);
    unsigned short* Kb  = Qb + elems;
    unsigned short* Vtb = Kb + elems;

    int ptiles = (T + 63) / 64;
    dim3 pgrid(ptiles, HEADS, 3);
    prep_kernel<<<pgrid, 256, 0, stream>>>(qkv, Qb, Kb, Vtb, T);

    int tiles = (T + TQ - 1) / TQ;
    dim3 grid(tiles, HEADS, NSPLIT);
    fa_main<<<grid, 256, 0, stream>>>(Qb, Kb, Vtb, cu, n_cu, T, out, Opart, Mpp, Lpp);

    int total4 = T * HEADS * (DH / 4);
    fa_combine_kernel<<<(total4 + 255) / 256, 256, 0, stream>>>(Opart, Mpp, Lpp, out, T);
}

// Round 6
// 109.435 us; speedup vs baseline: 1.0219x; 1.0219x over previous
//
#include <hip/hip_runtime.h>

// Varlen non-causal attention, qkv-packed (T,3,H,D) fp32 in/out.
// 3-kernel pipeline:
//  1) prep:    fp32 qkv -> bf16 Kb[h][t][d], Vtb[h][d][t]  (Q converted in main)
//  2) main:    bf16 MFMA flash attention, TQ=64, split-K x2.
//              K/V double-buffered in LDS via global_load_lds(16B) with XOR
//              swizzle; prefetch for chunk c+1 issued right after the single
//              per-chunk barrier -> load latency overlapped with compute.
//  3) combine: merge split-K partials (m,l,O) -> out

#define HEADS 8
#define DH 64
#define TQ 64
#define TK 64
#define PSTR 72
#define NSPLIT 2
#define NEG_BIG -1e30f
#define L2E 1.44269504088896340736f

using f32x4 = __attribute__((ext_vector_type(4))) float;
using s16x8 = __attribute__((ext_vector_type(8))) short;

__device__ inline unsigned short bf16b(float x) {
    union { float f; unsigned u; } c; c.f = x;
    unsigned r = c.u + 0x7fffu + ((c.u >> 16) & 1u);   // RNE
    return (unsigned short)(r >> 16);
}

#if __has_builtin(__builtin_amdgcn_cvt_pk_bf16_f32)
__device__ inline unsigned pk2(float a, float b) {
    auto v = __builtin_amdgcn_cvt_pk_bf16_f32(a, b);
    unsigned u; __builtin_memcpy(&u, &v, 4); return u;
}
#else
__device__ inline unsigned pk2(float a, float b) {
    return (unsigned)bf16b(a) | ((unsigned)bf16b(b) << 16);
}
#endif

// ---------------- pre-pass: convert + re-layout K,V ----------------
__global__ __launch_bounds__(256)
void prep_kernel(const float* __restrict__ qkv, unsigned short* __restrict__ Kb,
                 unsigned short* __restrict__ Vtb, int T) {
    __shared__ unsigned short Lt[64][PSTR];
    const int m = blockIdx.z + 1;          // 1 = K, 2 = V
    const int h = blockIdx.y, t0 = blockIdx.x * 64;
    const int tid = threadIdx.x, d8 = tid & 7, tr = tid >> 3;   // tr 0..31

    #pragma unroll
    for (int i = 0; i < 2; ++i) {
        int t = t0 + i * 32 + tr;
        int tc = t < T ? t : T - 1;
        const float* src = qkv + ((size_t)tc * 3 + m) * (HEADS * DH) + h * DH + d8 * 8;
        float4 a = *(const float4*)src;
        float4 b = *(const float4*)(src + 4);
        unsigned p0 = pk2(a.x, a.y), p1 = pk2(a.z, a.w);
        unsigned p2 = pk2(b.x, b.y), p3 = pk2(b.z, b.w);
        if (m == 2) {
            *(uint2*)&Lt[i * 32 + tr][d8 * 8]     = make_uint2(p0, p1);
            *(uint2*)&Lt[i * 32 + tr][d8 * 8 + 4] = make_uint2(p2, p3);
        } else if (t < T) {
            *(uint4*)(Kb + ((size_t)h * T + t) * DH + d8 * 8) = make_uint4(p0, p1, p2, p3);
        }
    }
    if (m == 2) {
        __syncthreads();
        const int d = tid >> 2, tg = tid & 3;
        #pragma unroll
        for (int p = 0; p < 2; ++p) {
            int G = tg + 4 * p;
            int td = t0 + G * 8;
            unsigned u[4];
            #pragma unroll
            for (int jj = 0; jj < 4; ++jj)
                u[jj] = (unsigned)Lt[G * 8 + 2 * jj][d] |
                        ((unsigned)Lt[G * 8 + 2 * jj + 1][d] << 16);
            if (td < T)
                *(uint4*)(Vtb + ((size_t)h * DH + d) * T + td) =
                    make_uint4(u[0], u[1], u[2], u[3]);
        }
    }
}

// ---------------- main flash kernel ----------------
__global__ __launch_bounds__(256, 3)
void fa_main(const float* __restrict__ qkv, const unsigned short* __restrict__ Kb,
             const unsigned short* __restrict__ Vtb, const int* __restrict__ cu,
             int n_cu, int T, float* __restrict__ out,
             float* __restrict__ Opart, float* __restrict__ Mp, float* __restrict__ Lp) {
    __shared__ unsigned short Ksh[2][TK * DH];   // swizzled: g = row*8 + (gd^(row&7))
    __shared__ unsigned short Vsh[2][TK * DH];
    __shared__ unsigned short Psh[TQ][PSTR];

    const int tid = threadIdx.x;
    const int h = blockIdx.y, t0 = blockIdx.x * TQ;
    const int split = blockIdx.z, nsplit = gridDim.z;
    const int w = tid >> 6, lane = tid & 63, n15 = lane & 15, quad = lane >> 4;

    // ---- segment bounds ----
    int trow = t0 + w * 16 + n15; if (trow > T - 1) trow = T - 1;
    int lo, hi;
    { int s = 0; for (int j = 1; j < n_cu - 1; ++j) if (cu[j] <= trow) s = j;
      lo = cu[s]; hi = cu[s + 1]; }
    int kb_, ke;
    { int s = 0; for (int j = 1; j < n_cu - 1; ++j) if (cu[j] <= t0) s = j;
      kb_ = cu[s];
      int tl = t0 + TQ - 1; if (tl > T - 1) tl = T - 1;
      s = 0; for (int j = 1; j < n_cu - 1; ++j) if (cu[j] <= tl) s = j;
      ke = cu[s + 1]; }

    // ---- Q fragments: load fp32, fold 0.125, pack bf16 ----
    s16x8 qfrag[2];
    {
        int tc = t0 + w * 16 + n15; if (tc > T - 1) tc = T - 1;
        const float* qp = qkv + (size_t)tc * 3 * (HEADS * DH) + h * DH + quad * 8;
        #pragma unroll
        for (int kh = 0; kh < 2; ++kh) {
            float4 a = *(const float4*)(qp + kh * 32);
            float4 b = *(const float4*)(qp + kh * 32 + 4);
            unsigned u0 = pk2(a.x * 0.125f, a.y * 0.125f);
            unsigned u1 = pk2(a.z * 0.125f, a.w * 0.125f);
            unsigned u2 = pk2(b.x * 0.125f, b.y * 0.125f);
            unsigned u3 = pk2(b.z * 0.125f, b.w * 0.125f);
            uint4 uu = make_uint4(u0, u1, u2, u3);
            __builtin_memcpy(&qfrag[kh], &uu, 16);
        }
    }

    // ---- staging lane constants ----
    const unsigned short* kb_h = Kb + (size_t)h * T * DH;
    const unsigned short* vt_h = Vtb + (size_t)h * DH * T;
    int krow_rel[2], vkey_off[2], ldst[2];
    const unsigned short* kbase[2];
    const unsigned short* vbase[2];
    #pragma unroll
    for (int i = 0; i < 2; ++i) {
        int gg = i * 64 + lane;
        int rr = gg >> 3;
        int gc = gg & 7;
        int row = w * 16 + rr;            // 0..63
        int gcol = gc ^ (row & 7);
        krow_rel[i] = row;
        kbase[i] = kb_h + gcol * 8;
        vbase[i] = vt_h + (size_t)row * T;
        vkey_off[i] = gcol * 8;
        ldst[i] = (w * 128 + i * 64) * 8;
    }
    int off16[2];
    #pragma unroll
    for (int kh = 0; kh < 2; ++kh)
        off16[kh] = n15 * 128 + (((kh * 4 + quad) ^ (n15 & 7)) * 16);

    f32x4 oacc[4];
    #pragma unroll
    for (int i = 0; i < 4; ++i) oacc[i] = (f32x4){0.f, 0.f, 0.f, 0.f};
    float m_ = NEG_BIG, l_ = 0.f;

    const int step = nsplit * TK;
    const int c0_start = (kb_ / TK) * TK + split * TK;

    // ---- prologue: stage chunk 0 into buffer 0 ----
    #pragma unroll
    for (int i = 0; i < 2; ++i) {
        int rk = c0_start + krow_rel[i]; if (rk > T - 1) rk = T - 1;
        __builtin_amdgcn_global_load_lds(
            (const __attribute__((address_space(1))) void*)(kbase[i] + ((size_t)rk << 6)),
            (__attribute__((address_space(3))) void*)&Ksh[0][ldst[i]], 16, 0, 0);
        int kv = c0_start + vkey_off[i]; if (kv > T - 8) kv = T - 8;
        __builtin_amdgcn_global_load_lds(
            (const __attribute__((address_space(1))) void*)(vbase[i] + kv),
            (__attribute__((address_space(3))) void*)&Vsh[0][ldst[i]], 16, 0, 0);
    }

    int ib = 0;
    for (int c0 = c0_start; c0 < ke; c0 += step, ib ^= 1) {
        // single barrier per chunk: completes stage(buf ib) AND fences
        // last iteration's reads of buf ib^1 before we restage it below
        __syncthreads();

        // ---- prefetch next chunk into the other buffer (overlaps compute) ----
        int cn = c0 + step;
        if (cn < ke) {
            #pragma unroll
            for (int i = 0; i < 2; ++i) {
                int rk = cn + krow_rel[i]; if (rk > T - 1) rk = T - 1;
                __builtin_amdgcn_global_load_lds(
                    (const __attribute__((address_space(1))) void*)(kbase[i] + ((size_t)rk << 6)),
                    (__attribute__((address_space(3))) void*)&Ksh[ib ^ 1][ldst[i]], 16, 0, 0);
                int kv = cn + vkey_off[i]; if (kv > T - 8) kv = T - 8;
                __builtin_amdgcn_global_load_lds(
                    (const __attribute__((address_space(1))) void*)(vbase[i] + kv),
                    (__attribute__((address_space(3))) void*)&Vsh[ib ^ 1][ldst[i]], 16, 0, 0);
            }
        }

        // ---- S^T = K·Q^T : lane holds S[q=n15][key = nt*16 + quad*4 + reg] ----
        const char* Kc = (const char*)Ksh[ib];
        f32x4 sacc[4];
        #pragma unroll
        for (int nt = 0; nt < 4; ++nt) {
            s16x8 k0 = *(const s16x8*)(Kc + nt * 2048 + off16[0]);
            s16x8 k1 = *(const s16x8*)(Kc + nt * 2048 + off16[1]);
            f32x4 z = (f32x4){0.f, 0.f, 0.f, 0.f};
            z = __builtin_amdgcn_mfma_f32_16x16x32_bf16(k0, qfrag[0], z, 0, 0, 0);
            z = __builtin_amdgcn_mfma_f32_16x16x32_bf16(k1, qfrag[1], z, 0, 0, 0);
            sacc[nt] = z;
        }

        // ---- mask (boundary chunks only) ----
        if (!(c0 >= lo && c0 + TK <= hi)) {
            #pragma unroll
            for (int nt = 0; nt < 4; ++nt)
                #pragma unroll
                for (int reg = 0; reg < 4; ++reg) {
                    int key = c0 + nt * 16 + quad * 4 + reg;
                    bool valid = (key >= lo) && (key < hi);
                    sacc[nt][reg] = valid ? sacc[nt][reg] : NEG_BIG;
                }
        }

        // ---- online softmax (row = n15; reduce across quad lanes) ----
        float rm = NEG_BIG;
        #pragma unroll
        for (int nt = 0; nt < 4; ++nt)
            #pragma unroll
            for (int reg = 0; reg < 4; ++reg) rm = fmaxf(rm, sacc[nt][reg]);
        rm = fmaxf(rm, __shfl_xor(rm, 16));
        rm = fmaxf(rm, __shfl_xor(rm, 32));
        float mn = fmaxf(m_, rm);
        float alpha = exp2f((m_ - mn) * L2E);
        float mnl = mn * L2E;
        float rs = 0.f;
        #pragma unroll
        for (int nt = 0; nt < 4; ++nt) {
            float p0 = exp2f(fmaf(sacc[nt][0], L2E, -mnl));
            float p1 = exp2f(fmaf(sacc[nt][1], L2E, -mnl));
            float p2 = exp2f(fmaf(sacc[nt][2], L2E, -mnl));
            float p3 = exp2f(fmaf(sacc[nt][3], L2E, -mnl));
            rs += (p0 + p1) + (p2 + p3);
            *(uint2*)&Psh[w * 16 + n15][nt * 16 + quad * 4] =
                make_uint2(pk2(p0, p1), pk2(p2, p3));
        }
        rs += __shfl_xor(rs, 16);
        rs += __shfl_xor(rs, 32);
        l_ = fmaf(l_, alpha, rs);
        m_ = mn;
        #pragma unroll
        for (int reg = 0; reg < 4; ++reg) {
            float ar = __shfl(alpha, quad * 4 + reg);
            oacc[0][reg] *= ar; oacc[1][reg] *= ar;
            oacc[2][reg] *= ar; oacc[3][reg] *= ar;
        }

        // ---- PV: O += P·V (Psh rows wave-private: no barrier needed) ----
        s16x8 afr[2];
        afr[0] = *(const s16x8*)&Psh[w * 16 + n15][quad * 8];
        afr[1] = *(const s16x8*)&Psh[w * 16 + n15][32 + quad * 8];
        const char* Vc = (const char*)Vsh[ib];
        #pragma unroll
        for (int nt = 0; nt < 4; ++nt) {
            s16x8 v0 = *(const s16x8*)(Vc + nt * 2048 + off16[0]);
            s16x8 v1 = *(const s16x8*)(Vc + nt * 2048 + off16[1]);
            oacc[nt] = __builtin_amdgcn_mfma_f32_16x16x32_bf16(afr[0], v0, oacc[nt], 0, 0, 0);
            oacc[nt] = __builtin_amdgcn_mfma_f32_16x16x32_bf16(afr[1], v1, oacc[nt], 0, 0, 0);
        }
    }

    // ---- epilogue ----
    if (nsplit == 1) {
        #pragma unroll
        for (int reg = 0; reg < 4; ++reg) {
            float lr = __shfl(l_, quad * 4 + reg);
            float inv = 1.f / fmaxf(lr, 1e-30f);
            int t = t0 + w * 16 + quad * 4 + reg;
            if (t < T) {
                #pragma unroll
                for (int nt = 0; nt < 4; ++nt)
                    out[((size_t)t * HEADS + h) * DH + nt * 16 + n15] = oacc[nt][reg] * inv;
            }
        }
    } else {
        #pragma unroll
        for (int reg = 0; reg < 4; ++reg) {
            int t = t0 + w * 16 + quad * 4 + reg;
            if (t < T) {
                size_t base = (((size_t)split * T + t) * HEADS + h) * DH;
                #pragma unroll
                for (int nt = 0; nt < 4; ++nt)
                    Opart[base + nt * 16 + n15] = oacc[nt][reg];
            }
        }
        int tq = t0 + w * 16 + n15;
        if (quad == 0 && tq < T) {
            size_t mi = ((size_t)split * T + tq) * HEADS + h;
            Mp[mi] = m_; Lp[mi] = l_;
        }
    }
}

// ---------------- split-K combine ----------------
__global__ __launch_bounds__(256)
void fa_combine_kernel(const float* __restrict__ Opart, const float* __restrict__ Mp,
                       const float* __restrict__ Lp, float* __restrict__ out, int T) {
    int i4 = blockIdx.x * blockDim.x + threadIdx.x;
    int total = T * HEADS * (DH / 4);
    if (i4 >= total) return;
    int th = i4 / (DH / 4);
    int d4 = i4 - th * (DH / 4);
    size_t stride = (size_t)T * HEADS * DH;
    int mlstride = T * HEADS;
    float m[NSPLIT], l[NSPLIT];
    float M = NEG_BIG;
    #pragma unroll
    for (int s = 0; s < NSPLIT; ++s) {
        m[s] = Mp[(size_t)s * mlstride + th];
        l[s] = Lp[(size_t)s * mlstride + th];
        M = fmaxf(M, m[s]);
    }
    float L = 0.f, wgt[NSPLIT];
    #pragma unroll
    for (int s = 0; s < NSPLIT; ++s) {
        wgt[s] = exp2f((m[s] - M) * L2E);
        L = fmaf(l[s], wgt[s], L);
    }
    float inv = 1.f / fmaxf(L, 1e-30f);
    size_t off = (size_t)th * DH + 4 * d4;
    float4 o = make_float4(0.f, 0.f, 0.f, 0.f);
    #pragma unroll
    for (int s = 0; s < NSPLIT; ++s) {
        float4 a = *(const float4*)&Opart[(size_t)s * stride + off];
        float ws = wgt[s];
        o.x = fmaf(a.x, ws, o.x); o.y = fmaf(a.y, ws, o.y);
        o.z = fmaf(a.z, ws, o.z); o.w = fmaf(a.w, ws, o.w);
    }
    o.x *= inv; o.y *= inv; o.z *= inv; o.w *= inv;
    *(float4*)&out[off] = o;
}

extern "C" void kernel_launch(void* const* d_in, const int* in_sizes, int n_in,
                              void* d_out, int out_size, void* d_ws, size_t ws_size,
                              hipStream_t stream) {
    const float* qkv = (const float*)d_in[0];
    const int* cu    = (const int*)d_in[1];
    const int n_cu   = in_sizes[1];
    const int T      = in_sizes[0] / (3 * HEADS * DH);
    float* out       = (float*)d_out;

    size_t elems = (size_t)T * HEADS * DH;

    float* Opart = (float*)d_ws;                                  // NSPLIT*elems f32
    float* Mpp   = Opart + (size_t)NSPLIT * elems;                // NSPLIT*T*H f32
    float* Lpp   = Mpp + (size_t)NSPLIT * T * HEADS;
    unsigned short* Kb  = (unsigned short*)(Lpp + (size_t)NSPLIT * T * HEADS);
    unsigned short* Vtb = Kb + elems;

    int ptiles = (T + 63) / 64;
    dim3 pgrid(ptiles, HEADS, 2);
    prep_kernel<<<pgrid, 256, 0, stream>>>(qkv, Kb, Vtb, T);

    int tiles = (T + TQ - 1) / TQ;
    dim3 grid(tiles, HEADS, NSPLIT);
    fa_main<<<grid, 256, 0, stream>>>(qkv, Kb, Vtb, cu, n_cu, T, out, Opart, Mpp, Lpp);

    int total4 = T * HEADS * (DH / 4);
    fa_combine_kernel<<<(total4 + 255) / 256, 256, 0, stream>>>(Opart, Mpp, Lpp, out, T);
}